// Round 15
// baseline (47.800 us; speedup 1.0000x reference)
//
#include <hip/hip_runtime.h>

// SoftHistLoss: x,y [16,3,512,512] f32 -> scalar f32
// R15: ZERO LDS OPS IN HOT LOOP - per-thread VGPR bin accumulators.
// R14 lesson: binding pipe was the LDS-atomic pipe (~35cyc/wave-op x 1536/CU
// ~= 22us); R10 ~= R14 despite 12-VALU/px delta proved VALU wasn't binding.
// Packed word (R10-proven): pk = BASE + (trunc(s*scale) << sel),
//   BASE=(255<<18)+1; qa<=255 @[31:18] (64px sum 16320<2^14),
//   qb<=31 @[17:7] (sum 1984<2^11), count @[6:0] (64<2^7).
// Single-sigmoid: m=0.5-|d-0.5|, s=sigma(-15m):
//   d<0.5: qa=255-trunc(255s), qb=0;  d>=0.5: qa=255, qb=trunc(62s).
// Hot loop/px: ~14 VALU + 2 trans for pk, then 10x {cmp,cndmask,add} into
// acc[10] (all compile-time indices -> registers, no scratch). VALU runs
// 4 instr/cyc/CU vs LDS pipe 1 op/~35cyc -> ~32K cyc/SIMD ~= 14us.
// k clamped to 9: v==1.0 handled EXACTLY (d=1 -> qa=255,qb=31 -> +0.5 to bin9).
// hist_i = A[i]-B[i]+B[i-1]+C[i+1]-A[i+1]; epilogue = plain ds_writes +
// R10's integer stage-1/2 reduce; global integer atomics (deterministic).
// Lessons kept: no FP LDS atomics (R2), no dependent LDS reads in hot loop
// (R9), no fat fused epilogue (R11), 1536 blocks = one occupancy round (R7).

static constexpr int PLANES   = 48;               // 16*3 per image
static constexpr int PLANE_PX = 512 * 512;
static constexpr int SPP      = 16;               // sub-blocks per plane
static constexpr int THREADS  = 256;
static constexpr int CHUNK    = PLANE_PX / SPP;   // 16384 px/block, 64 px/thread
static constexpr int NBLK     = 96 * SPP;         // 1536 = 6 blocks/CU, one round
static constexpr unsigned BASE = (255u << 18) + 1u;

__global__ __launch_bounds__(THREADS, 6) void soft_hist_partial(
    const float* __restrict__ xin, const float* __restrict__ yin,
    unsigned* __restrict__ G /* [96][30] u32: per plane {A,B,C} x 10 bins */)
{
  __shared__ unsigned hist[10 * THREADS];         // epilogue merge only
  __shared__ unsigned red[10 * 16 * 3];
  const int t = threadIdx.x;

  const int blk   = blockIdx.x;
  const int plane = blk >> 4;                     // 0..95 (0..47 = x, 48..95 = y)
  const int sub   = blk & 15;
  const float* src = (plane < PLANES ? xin + (size_t)plane * PLANE_PX
                                     : yin + (size_t)(plane - PLANES) * PLANE_PX)
                   + (size_t)sub * CHUNK;
  const float4* src4 = (const float4*)src;

  unsigned acc[10];
  #pragma unroll
  for (int b = 0; b < 10; ++b) acc[b] = 0u;

  constexpr int ITERS = CHUNK / (THREADS * 4);    // 16
  float4 c0 = src4[t];
  float4 c1 = src4[THREADS + t];
  #pragma unroll 4
  for (int it = 0; it < ITERS; ++it) {
    float4 cur = c0;
    c0 = c1;
    if (it + 2 < ITERS) c1 = src4[(it + 2) * THREADS + t];
    float vv[4] = {cur.x, cur.y, cur.z, cur.w};
    #pragma unroll
    for (int j = 0; j < 4; ++j) {
      float W  = vv[j] * 10.0f;                   // [0,10]
      unsigned k = (unsigned)W;                   // trunc
      k = k > 9u ? 9u : k;                        // v==1.0 -> bin 9 (exact)
      float d  = W - floorf(W);                   // v_fract; v==1.0 -> d=... W=10
      if (k == 9u && W >= 10.0f) d = 1.0f;        // folds to cndmask; exactness
      float mp = d - 0.5f;
      bool lo  = mp < 0.0f;
      float ex = __expf(fmaf(-15.0f, fabsf(mp), 7.5f));   // e^{7.5-15|mp|}
      float sg = __builtin_amdgcn_rcpf(1.0f + ex);        // sigma(-15m)
      float scale = lo ? -255.0f : 62.0f;
      int   qs = (int)(sg * scale);               // trunc toward 0
      unsigned sel = lo ? 18u : 7u;
      unsigned pk  = ((unsigned)qs << sel) + BASE;
      #pragma unroll
      for (int b = 0; b < 10; ++b)                // 10x cmp+cndmask+add, VGPRs
        acc[b] += (k == (unsigned)b) ? pk : 0u;
    }
  }

  // ---- epilogue: one conflict-free ds_write per bin, then integer reduce ----
  #pragma unroll
  for (int b = 0; b < 10; ++b) hist[(b << 8) + t] = acc[b];
  __syncthreads();

  // stage 1: 160 threads, each sums 16 columns of one bin (unpacked fields)
  if (t < 160) {
    const int bin = t >> 4, grp = t & 15;
    const uint4* hp = (const uint4*)(hist + (bin << 8) + (grp << 4));
    unsigned sa = 0, sb = 0, sc = 0;
    #pragma unroll
    for (int q = 0; q < 4; ++q) {
      uint4 u4 = hp[q];
      unsigned uu[4] = {u4.x, u4.y, u4.z, u4.w};
      #pragma unroll
      for (int e = 0; e < 4; ++e) {
        unsigned u = uu[e];
        sa += u >> 18; sb += (u >> 7) & 0x7FFu; sc += u & 0x7Fu;
      }
    }
    const int base = (bin * 16 + grp) * 3;
    red[base] = sa; red[base + 1] = sb; red[base + 2] = sc;
  }
  __syncthreads();

  // stage 2: 30 threads -> global integer atomics (deterministic)
  if (t < 30) {
    const int bin = t / 3, c = t - 3 * bin;
    unsigned s = 0;
    #pragma unroll
    for (int g = 0; g < 16; ++g) s += red[(bin * 16 + g) * 3 + c];
    atomicAdd(&G[plane * 30 + bin * 3 + c], s);
  }
}

__global__ __launch_bounds__(512) void soft_hist_loss(
    const unsigned* __restrict__ G, float* __restrict__ out)
{
  __shared__ float wred[8];
  const int t = threadIdx.x;
  float val = 0.0f;
  if (t < 480) {
    const int pc = t / 10;        // (batch,channel) 0..47
    const int i  = t - pc * 10;   // bin
    const unsigned* gx = G + pc * 30;
    const unsigned* gy = G + (pc + PLANES) * 30;
    // hist_i = A[i]/255 - B[i]/62 + B[i-1]/62 + C[i+1] - A[i+1]/255
    float hx = (float)gx[3 * i] * (1.0f / 255.0f)
             - (float)gx[3 * i + 1] * (1.0f / 62.0f)
             + (i > 0 ? (float)gx[3 * (i - 1) + 1] * (1.0f / 62.0f) : 0.0f)
             + (i < 9 ? (float)gx[3 * (i + 1) + 2]
                      - (float)gx[3 * (i + 1)] * (1.0f / 255.0f) : 0.0f);
    float hy = (float)gy[3 * i] * (1.0f / 255.0f)
             - (float)gy[3 * i + 1] * (1.0f / 62.0f)
             + (i > 0 ? (float)gy[3 * (i - 1) + 1] * (1.0f / 62.0f) : 0.0f)
             + (i < 9 ? (float)gy[3 * (i + 1) + 2]
                      - (float)gy[3 * (i + 1)] * (1.0f / 255.0f) : 0.0f);
    val = fabsf(hx - hy);
  }
  #pragma unroll
  for (int off = 32; off >= 1; off >>= 1) val += __shfl_xor(val, off, 64);
  if ((t & 63) == 0) wred[t >> 6] = val;
  __syncthreads();
  if (t == 0) {
    float s = 0.0f;
    #pragma unroll
    for (int w = 0; w < 8; ++w) s += wred[w];
    // loss = sum * (1/BINS) * (1/B) * 1e-4
    out[0] = s * 6.25e-7f;
  }
}

extern "C" void kernel_launch(void* const* d_in, const int* in_sizes, int n_in,
                              void* d_out, int out_size, void* d_ws, size_t ws_size,
                              hipStream_t stream) {
  const float* x = (const float*)d_in[0];
  const float* y = (const float*)d_in[1];
  unsigned* G = (unsigned*)d_ws;               // 96*30*4 = 11520 B
  hipMemsetAsync(d_ws, 0, 96 * 30 * sizeof(unsigned), stream);
  soft_hist_partial<<<NBLK, THREADS, 0, stream>>>(x, y, G);
  soft_hist_loss<<<1, 512, 0, stream>>>(G, (float*)d_out);
}

// Round 16
// 36.824 us; speedup vs baseline: 1.2981x; 1.2981x over previous
//
#include <hip/hip_runtime.h>

// SoftHistLoss: x,y [16,3,512,512] f32 -> scalar f32
// R16: PIPE-SPLIT hot loop. Measured pipe economics (R10/R13/R14/R15):
//   - LDS-atomic pipe: ~42 cyc per wave ds_add (2 lanes/bank) -> 1 op/px = ~27us
//   - VALU: sigmoid ~17 instr = cheap; +10-way cndmask chain ~45 instr = ~26us
// Neither pipe alone beats ~26us; they run CONCURRENTLY -> split pixels:
//   even j -> ds_add_u32 into hist[k][t]   (LDS pipe, 768 ops/CU ~ 13us)
//   odd  j -> VGPR acc[10] cndmask chain   (VALU pipe, ~30 instr/px avg ~ 10us)
// Packed word (R10-proven): pk = BASE + (trunc(s*scale) << sel),
//   BASE=(255<<18)+1; qa @[31:18], qb @[17:7], count @[6:0].
//   Per-column total stays <=64 px (32 atomic + 32 via acc merge) -> fields fit.
// Single-sigmoid: m=0.5-|d-0.5|, s=sigma(-15m):
//   d<0.5: qa=255-trunc(255s), qb=0;  d>=0.5: qa=255, qb=trunc(62s).
// hist_i = A[i]-B[i]+B[i-1]+C[i+1]-A[i+1]; integer reduce + global int atomics.
// Lessons kept: no FP LDS atomics (R2); no dependent LDS reads in hot loop
// (R9); no fat fused epilogue (R11); one occupancy round (R7); compile-time
// acc indices only (R15/rule: runtime-indexed arrays -> scratch).

static constexpr int PLANES   = 48;               // 16*3 per image
static constexpr int PLANE_PX = 512 * 512;
static constexpr int SPP      = 16;               // sub-blocks per plane
static constexpr int THREADS  = 256;
static constexpr int CHUNK    = PLANE_PX / SPP;   // 16384 px/block, 64 px/thread
static constexpr int NBLK     = 96 * SPP;         // 1536 = 6 blocks/CU, one round
static constexpr unsigned BASE = (255u << 18) + 1u;

__global__ __launch_bounds__(THREADS, 6) void soft_hist_partial(
    const float* __restrict__ xin, const float* __restrict__ yin,
    unsigned* __restrict__ G /* [96][30] u32: per plane {A,B,C} x 10 bins */)
{
  __shared__ unsigned hist[10 * THREADS];         // 10240 B
  __shared__ unsigned red[10 * 16 * 3];           // 1920 B
  const int t = threadIdx.x;
  #pragma unroll
  for (int s = 0; s < 10; ++s) hist[s * THREADS + t] = 0u;
  __syncthreads();

  const int blk   = blockIdx.x;
  const int plane = blk >> 4;                     // 0..95 (0..47 = x, 48..95 = y)
  const int sub   = blk & 15;
  const float* src = (plane < PLANES ? xin + (size_t)plane * PLANE_PX
                                     : yin + (size_t)(plane - PLANES) * PLANE_PX)
                   + (size_t)sub * CHUNK;
  const float4* src4 = (const float4*)src;
  unsigned* mycol = hist + t;

  unsigned acc[10];
  #pragma unroll
  for (int b = 0; b < 10; ++b) acc[b] = 0u;

  constexpr int ITERS = CHUNK / (THREADS * 4);    // 16
  float4 c0 = src4[t];
  float4 c1 = src4[THREADS + t];
  #pragma unroll 4
  for (int it = 0; it < ITERS; ++it) {
    float4 cur = c0;
    c0 = c1;
    if (it + 2 < ITERS) c1 = src4[(it + 2) * THREADS + t];
    float vv[4] = {cur.x, cur.y, cur.z, cur.w};
    #pragma unroll
    for (int j = 0; j < 4; ++j) {
      float W  = vv[j] * 10.0f;                   // [0,10)
      unsigned k = (unsigned)W;                   // trunc
      k = k > 9u ? 9u : k;                        // safety clamp
      float d  = W - floorf(W);                   // v_fract
      float mp = d - 0.5f;
      bool lo  = mp < 0.0f;
      float ex = __expf(fmaf(-15.0f, fabsf(mp), 7.5f));   // e^{7.5-15|mp|}
      float sg = __builtin_amdgcn_rcpf(1.0f + ex);        // sigma(-15m)
      float scale = lo ? -255.0f : 62.0f;
      int   qs = (int)(sg * scale);               // trunc toward 0
      unsigned sel = lo ? 18u : 7u;
      unsigned pk  = ((unsigned)qs << sel) + BASE;
      if (j & 1) {
        // VALU pipe: compile-time-indexed VGPR accumulators
        #pragma unroll
        for (int b = 0; b < 10; ++b)
          acc[b] += (k == (unsigned)b) ? pk : 0u;
      } else {
        // LDS pipe: fire-and-forget native atomic, bank = t%32 (2 lanes/bank)
        atomicAdd(&mycol[k << 8], pk);            // ds_add_u32
      }
    }
  }

  // merge VGPR accumulators into the same columns (total <= 64 px/column)
  #pragma unroll
  for (int b = 0; b < 10; ++b) atomicAdd(&mycol[b << 8], acc[b]);
  __syncthreads();

  // stage 1: 160 threads, each sums 16 columns of one bin (unpacked fields)
  if (t < 160) {
    const int bin = t >> 4, grp = t & 15;
    const uint4* hp = (const uint4*)(hist + (bin << 8) + (grp << 4));
    unsigned sa = 0, sb = 0, sc = 0;
    #pragma unroll
    for (int q = 0; q < 4; ++q) {
      uint4 u4 = hp[q];
      unsigned uu[4] = {u4.x, u4.y, u4.z, u4.w};
      #pragma unroll
      for (int e = 0; e < 4; ++e) {
        unsigned u = uu[e];
        sa += u >> 18; sb += (u >> 7) & 0x7FFu; sc += u & 0x7Fu;
      }
    }
    const int base = (bin * 16 + grp) * 3;
    red[base] = sa; red[base + 1] = sb; red[base + 2] = sc;
  }
  __syncthreads();

  // stage 2: 30 threads -> global integer atomics (deterministic)
  if (t < 30) {
    const int bin = t / 3, c = t - 3 * bin;
    unsigned s = 0;
    #pragma unroll
    for (int g = 0; g < 16; ++g) s += red[(bin * 16 + g) * 3 + c];
    atomicAdd(&G[plane * 30 + bin * 3 + c], s);
  }
}

__global__ __launch_bounds__(512) void soft_hist_loss(
    const unsigned* __restrict__ G, float* __restrict__ out)
{
  __shared__ float wred[8];
  const int t = threadIdx.x;
  float val = 0.0f;
  if (t < 480) {
    const int pc = t / 10;        // (batch,channel) 0..47
    const int i  = t - pc * 10;   // bin
    const unsigned* gx = G + pc * 30;
    const unsigned* gy = G + (pc + PLANES) * 30;
    // hist_i = A[i]/255 - B[i]/62 + B[i-1]/62 + C[i+1] - A[i+1]/255
    float hx = (float)gx[3 * i] * (1.0f / 255.0f)
             - (float)gx[3 * i + 1] * (1.0f / 62.0f)
             + (i > 0 ? (float)gx[3 * (i - 1) + 1] * (1.0f / 62.0f) : 0.0f)
             + (i < 9 ? (float)gx[3 * (i + 1) + 2]
                      - (float)gx[3 * (i + 1)] * (1.0f / 255.0f) : 0.0f);
    float hy = (float)gy[3 * i] * (1.0f / 255.0f)
             - (float)gy[3 * i + 1] * (1.0f / 62.0f)
             + (i > 0 ? (float)gy[3 * (i - 1) + 1] * (1.0f / 62.0f) : 0.0f)
             + (i < 9 ? (float)gy[3 * (i + 1) + 2]
                      - (float)gy[3 * (i + 1)] * (1.0f / 255.0f) : 0.0f);
    val = fabsf(hx - hy);
  }
  #pragma unroll
  for (int off = 32; off >= 1; off >>= 1) val += __shfl_xor(val, off, 64);
  if ((t & 63) == 0) wred[t >> 6] = val;
  __syncthreads();
  if (t == 0) {
    float s = 0.0f;
    #pragma unroll
    for (int w = 0; w < 8; ++w) s += wred[w];
    // loss = sum * (1/BINS) * (1/B) * 1e-4
    out[0] = s * 6.25e-7f;
  }
}

extern "C" void kernel_launch(void* const* d_in, const int* in_sizes, int n_in,
                              void* d_out, int out_size, void* d_ws, size_t ws_size,
                              hipStream_t stream) {
  const float* x = (const float*)d_in[0];
  const float* y = (const float*)d_in[1];
  unsigned* G = (unsigned*)d_ws;               // 96*30*4 = 11520 B
  hipMemsetAsync(d_ws, 0, 96 * 30 * sizeof(unsigned), stream);
  soft_hist_partial<<<NBLK, THREADS, 0, stream>>>(x, y, G);
  soft_hist_loss<<<1, 512, 0, stream>>>(G, (float*)d_out);
}

// Round 17
// 33.092 us; speedup vs baseline: 1.4445x; 1.1128x over previous
//
#include <hip/hip_runtime.h>

// SoftHistLoss: x,y [16,3,512,512] f32 -> scalar f32
// R17: OCCUPANCY PLAY. Cost model from R10-R16: LDS-atomic ~10us, VALU ~5us,
// un-hidden feed/latency ~11-14us (OccupancyPercent stuck at 38-48%). All
// pipe-level rebalancing (R10/R14/R15/R16) plateaued at ~30us wall because
// the latency term is shared. Fix: 8 blocks/CU (2016 blocks, 32 waves/CU =
// 100% occupancy; launch_bounds(256,8) caps VGPR at 64) + prefetch depth 3.
// Inner math = R10 verbatim (proven absmax 2.44e-4):
//   pk = BASE + (trunc(s*scale) << sel), BASE=(255<<18)+1
//   m = 0.5-|d-0.5|, s = sigma(-15m); d<0.5 -> qa=255-trunc(255s);
//   d>=0.5 -> qb=trunc(62s).  Fields: qa[31:18] qb[17:7] cnt[6:0], <=64px/col.
// Plane split: subs 0-19 = 12288 px, sub 20 = 16384 px (20*12288+16384=262144).
// Lessons: no FP LDS atomics (R2); no dependent LDS reads in hot loop (R9);
// no fat fused epilogue (R11); pipes sum not overlap within a wave (R16).

static constexpr int PLANES   = 48;               // 16*3 per image
static constexpr int PLANE_PX = 512 * 512;        // 262144
static constexpr int SPP      = 21;               // sub-blocks per plane
static constexpr int THREADS  = 256;
static constexpr int NBLK     = 96 * SPP;         // 2016 ~= 8 blocks/CU
static constexpr unsigned BASE = (255u << 18) + 1u;

__global__ __launch_bounds__(THREADS, 8) void soft_hist_partial(
    const float* __restrict__ xin, const float* __restrict__ yin,
    unsigned* __restrict__ G /* [96][30] u32: per plane {A,B,C} x 10 bins */)
{
  __shared__ unsigned hist[11 * THREADS];         // 11264 B; row 10 = pad (v==1.0)
  __shared__ unsigned red[10 * 16 * 3];           // 1920 B
  const int t = threadIdx.x;
  #pragma unroll
  for (int s = 0; s < 11; ++s) hist[s * THREADS + t] = 0u;
  __syncthreads();

  const int blk   = blockIdx.x;
  const int plane = blk / SPP;                    // 0..95 (0..47 = x, 48..95 = y)
  const int sub   = blk - plane * SPP;            // 0..20
  const int iters = (sub == 20) ? 16 : 12;        // px/thread = 48 or 64
  const float* src = (plane < PLANES ? xin + (size_t)plane * PLANE_PX
                                     : yin + (size_t)(plane - PLANES) * PLANE_PX)
                   + (size_t)sub * 12288;
  const float4* src4 = (const float4*)src;
  unsigned* mycol = hist + t;

  float4 c0 = src4[t];
  float4 c1 = src4[THREADS + t];
  float4 c2 = src4[2 * THREADS + t];
  #pragma unroll 4
  for (int it = 0; it < iters; ++it) {
    float4 cur = c0;
    c0 = c1; c1 = c2;
    if (it + 3 < iters) c2 = src4[(it + 3) * THREADS + t];
    float vv[4] = {cur.x, cur.y, cur.z, cur.w};
    #pragma unroll
    for (int j = 0; j < 4; ++j) {
      float W  = vv[j] * 10.0f;                   // [0,10]
      unsigned k = (unsigned)W;                   // trunc; k=10 -> pad row
      float d  = W - floorf(W);                   // v_fract
      float mp = d - 0.5f;
      bool lo  = mp < 0.0f;
      float ex = __expf(fmaf(-15.0f, fabsf(mp), 7.5f));   // e^{7.5-15|mp|}
      float sg = __builtin_amdgcn_rcpf(1.0f + ex);        // sigma(-15m)
      float scale = lo ? -255.0f : 62.0f;
      int   qs = (int)(sg * scale);               // trunc toward 0
      unsigned sel = lo ? 18u : 7u;
      unsigned pk  = ((unsigned)qs << sel) + BASE;
      atomicAdd(&mycol[k << 8], pk);              // ds_add_u32, fire-and-forget
    }
  }
  __syncthreads();

  // stage 1: 160 threads, each sums 16 columns of one bin (unpacked fields)
  if (t < 160) {
    const int bin = t >> 4, grp = t & 15;
    const uint4* hp = (const uint4*)(hist + (bin << 8) + (grp << 4));
    unsigned sa = 0, sb = 0, sc = 0;
    #pragma unroll
    for (int q = 0; q < 4; ++q) {
      uint4 u4 = hp[q];
      unsigned uu[4] = {u4.x, u4.y, u4.z, u4.w};
      #pragma unroll
      for (int e = 0; e < 4; ++e) {
        unsigned u = uu[e];
        sa += u >> 18; sb += (u >> 7) & 0x7FFu; sc += u & 0x7Fu;
      }
    }
    const int base = (bin * 16 + grp) * 3;
    red[base] = sa; red[base + 1] = sb; red[base + 2] = sc;
  }
  __syncthreads();

  // stage 2: 30 threads -> global integer atomics (deterministic)
  if (t < 30) {
    const int bin = t / 3, c = t - 3 * bin;
    unsigned s = 0;
    #pragma unroll
    for (int g = 0; g < 16; ++g) s += red[(bin * 16 + g) * 3 + c];
    atomicAdd(&G[plane * 30 + bin * 3 + c], s);
  }
}

__global__ __launch_bounds__(512) void soft_hist_loss(
    const unsigned* __restrict__ G, float* __restrict__ out)
{
  __shared__ float wred[8];
  const int t = threadIdx.x;
  float val = 0.0f;
  if (t < 480) {
    const int pc = t / 10;        // (batch,channel) 0..47
    const int i  = t - pc * 10;   // bin
    const unsigned* gx = G + pc * 30;
    const unsigned* gy = G + (pc + PLANES) * 30;
    // hist_i = A[i]/255 - B[i]/62 + B[i-1]/62 + C[i+1] - A[i+1]/255
    float hx = (float)gx[3 * i] * (1.0f / 255.0f)
             - (float)gx[3 * i + 1] * (1.0f / 62.0f)
             + (i > 0 ? (float)gx[3 * (i - 1) + 1] * (1.0f / 62.0f) : 0.0f)
             + (i < 9 ? (float)gx[3 * (i + 1) + 2]
                      - (float)gx[3 * (i + 1)] * (1.0f / 255.0f) : 0.0f);
    float hy = (float)gy[3 * i] * (1.0f / 255.0f)
             - (float)gy[3 * i + 1] * (1.0f / 62.0f)
             + (i > 0 ? (float)gy[3 * (i - 1) + 1] * (1.0f / 62.0f) : 0.0f)
             + (i < 9 ? (float)gy[3 * (i + 1) + 2]
                      - (float)gy[3 * (i + 1)] * (1.0f / 255.0f) : 0.0f);
    val = fabsf(hx - hy);
  }
  #pragma unroll
  for (int off = 32; off >= 1; off >>= 1) val += __shfl_xor(val, off, 64);
  if ((t & 63) == 0) wred[t >> 6] = val;
  __syncthreads();
  if (t == 0) {
    float s = 0.0f;
    #pragma unroll
    for (int w = 0; w < 8; ++w) s += wred[w];
    // loss = sum * (1/BINS) * (1/B) * 1e-4
    out[0] = s * 6.25e-7f;
  }
}

extern "C" void kernel_launch(void* const* d_in, const int* in_sizes, int n_in,
                              void* d_out, int out_size, void* d_ws, size_t ws_size,
                              hipStream_t stream) {
  const float* x = (const float*)d_in[0];
  const float* y = (const float*)d_in[1];
  unsigned* G = (unsigned*)d_ws;               // 96*30*4 = 11520 B
  hipMemsetAsync(d_ws, 0, 96 * 30 * sizeof(unsigned), stream);
  soft_hist_partial<<<NBLK, THREADS, 0, stream>>>(x, y, G);
  soft_hist_loss<<<1, 512, 0, stream>>>(G, (float*)d_out);
}